// Round 3
// baseline (148.655 us; speedup 1.0000x reference)
//
#include <hip/hip_runtime.h>

// SATD loss: sum(|H8 @ (orig - pred)|) over [524288, 3, 8, 8] fp32 blocks.
// Memory-bound streaming: 805 MB read -> 1 scalar.
//
// Layout insight: flat float4 index f = block*16 + row*2 + colhalf. A wave's
// 64 lanes cover 4 whole blocks (wave base aligned to 64 float4s), and the
// 8 rows of a block differ only in bits 1..3 of the lane id. So:
//   - every load instruction is perfectly contiguous (lane l -> base + l*16B,
//     1 KiB per instruction, 100% cache-line utilization), and
//   - the row-wise FWHT-8 is 3 cross-lane butterfly stages (shfl_xor 2,4,8),
//     which lower to ds_swizzle and hide under HBM time.
// abs-sum is invariant to Hadamard output ordering/sign, so the natural FWHT
// order matches the reference sum exactly.

typedef float fvec4 __attribute__((ext_vector_type(4)));

__global__ __launch_bounds__(256) void satd_loss_kernel(
        const fvec4* __restrict__ orig, const fvec4* __restrict__ pred,
        float* __restrict__ out, int n4) {
    const int tid = blockIdx.x * blockDim.x + threadIdx.x;
    const int gstride = gridDim.x * blockDim.x;
    const int lane = threadIdx.x & 63;

    float acc = 0.0f;

    for (int base = tid; base < n4; base += gstride * 4) {
        fvec4 v[4];
        #pragma unroll
        for (int k = 0; k < 4; ++k) {
            const int idx = base + k * gstride;
            if (idx < n4) {
                fvec4 a = __builtin_nontemporal_load(&orig[idx]);
                fvec4 b = __builtin_nontemporal_load(&pred[idx]);
                v[k] = a - b;
            } else {
                v[k] = (fvec4)(0.f);
            }
        }

        #pragma unroll
        for (int k = 0; k < 4; ++k) {
            fvec4 t = v[k];
            // distributed FWHT-8 across lanes: rows live in lane bits 1..3
            #pragma unroll
            for (int m = 2; m <= 8; m <<= 1) {
                const bool hi = (lane & m) != 0;
                fvec4 p;
                p.x = __shfl_xor(t.x, m, 64);
                p.y = __shfl_xor(t.y, m, 64);
                p.z = __shfl_xor(t.z, m, 64);
                p.w = __shfl_xor(t.w, m, 64);
                fvec4 add = t + p;
                fvec4 sub = p - t;
                t = hi ? sub : add;
            }
            acc += fabsf(t.x) + fabsf(t.y) + fabsf(t.z) + fabsf(t.w);
        }
    }

    // wave-64 reduction
    #pragma unroll
    for (int off = 32; off > 0; off >>= 1)
        acc += __shfl_down(acc, off, 64);

    __shared__ float wsum[4];
    const int wid = threadIdx.x >> 6;
    if (lane == 0) wsum[wid] = acc;
    __syncthreads();

    if (threadIdx.x == 0) {
        float s = wsum[0] + wsum[1] + wsum[2] + wsum[3];
        atomicAdd(out, s);
    }
}

extern "C" void kernel_launch(void* const* d_in, const int* in_sizes, int n_in,
                              void* d_out, int out_size, void* d_ws, size_t ws_size,
                              hipStream_t stream) {
    const fvec4* orig = (const fvec4*)d_in[0];
    const fvec4* pred = (const fvec4*)d_in[1];
    float* out = (float*)d_out;

    const int nelem = in_sizes[0];   // 524288*3*64 = 100663296 floats
    const int n4 = nelem / 4;        // 25165824 float4s (divisible by 64)

    // harness poisons d_out; zero it every call (graph-capturable memset node)
    (void)hipMemsetAsync(out, 0, sizeof(float) * (size_t)out_size, stream);

    const int block = 256;
    const int grid = 4096;           // 1M threads, 6 outer iterations of K=4

    satd_loss_kernel<<<grid, block, 0, stream>>>(orig, pred, out, n4);
}